// Round 3
// baseline (212.087 us; speedup 1.0000x reference)
//
#include <hip/hip_runtime.h>

#define NCH 30
#define F2PC 15              // float2 per cell (120 B)
#define F4PP 15              // float4 per cell-PAIR (240 B, 16B-aligned)
#define THREADS 256

typedef float fvec2 __attribute__((ext_vector_type(2)));
typedef float fvec4 __attribute__((ext_vector_type(4)));

__device__ __forceinline__ float iou_fn(float x1, float y1, float w1, float h1,
                                        float x2, float y2, float w2, float h2) {
    float a1 = w1 * h1, a2 = w2 * h2;
    float left  = fmaxf(x1 - w1 * 0.5f, x2 - w2 * 0.5f);
    float right = fminf(x1 + w1 * 0.5f, x2 + w2 * 0.5f);
    float top   = fmaxf(y1 - h1 * 0.5f, y2 - h2 * 0.5f);
    float bot   = fminf(y1 + h1 * 0.5f, y2 + h2 * 0.5f);
    float iw = fmaxf(right - left, 0.0f);
    float ih = fmaxf(bot - top, 0.0f);
    float inter = iw * ih;
    float uni = a1 + a2 - inter;
    return (inter > 0.0f) ? (inter / uni) : 0.0f;
}

__device__ __forceinline__ void cell_losses(const float* p, const float* t,
                                            float& coord, float& lobj,
                                            float& lnoobj, float& lclass) {
    float obj_f = (t[0] == 1.0f) ? 1.0f : 0.0f;

    float iou1 = iou_fn(p[1], p[2], p[3], p[4], t[1], t[2], t[3], t[4]);
    float iou2 = iou_fn(t[6], t[7], t[8], t[9], t[1], t[2], t[3], t[4]);
    bool r = iou1 > iou2;

    float px = r ? p[1] : p[6], py = r ? p[2] : p[7];
    float pw = r ? p[3] : p[8], ph = r ? p[4] : p[9];
    float tx = r ? t[1] : t[6], ty = r ? t[2] : t[7];
    float tw = r ? t[3] : t[8], th = r ? t[4] : t[9];

    float dx = px - tx, dy = py - ty;
    float cxy = dx * dx + dy * dy;
    float swv = sqrtf(pw) - sqrtf(tw), shv = sqrtf(ph) - sqrtf(th);
    float cwh = swv * swv + shv * shv;

    float conf_resp  = r ? p[0] : p[5];
    float iou_resp   = r ? iou1 : iou2;
    float conf_other = r ? p[5] : p[0];
    float dconf = conf_resp - iou_resp;

    coord  += obj_f * (cxy + cwh);
    lobj   += obj_f * dconf * dconf;
    lnoobj += obj_f * conf_other * conf_other
            + (1.0f - obj_f) * (p[0] * p[0] + p[5] * p[5]);

    float cls = 0.0f;
#pragma unroll
    for (int i = 10; i < NCH; i++) { float e = p[i] - t[i]; cls += e * e; }
    lclass += obj_f * cls;
}

// Barrier-free: each thread owns a PAIR of adjacent cells (240 B = 15 float4,
// 16B-aligned since 240 % 16 == 0). No LDS, no __syncthreads in the hot path,
// no vmcnt(0) drains — latency hidden purely by TLP (~12 waves/CU, VGPR-bound).
// Address-path check: lane-stride-240 float4 loads cost <=64 lines/instr ->
// ~16 B/cy/CU worst-case vs 11.2 B/cy/CU needed for HBM rate; L1 absorbs the
// 4x sector re-touches.
__global__ __launch_bounds__(THREADS) void yolo_main(
        const fvec4* __restrict__ pred4, const fvec4* __restrict__ targ4,
        float4* __restrict__ partials, int n_pairs, int n_cells) {
    const int tid = threadIdx.x;
    float coord = 0.f, lobj = 0.f, lnoobj = 0.f, lclass = 0.f;

    // pair-stride loop: runs exactly once when grid covers all pairs (normal
    // case); loops only if the workspace forced a smaller grid.
    for (long long i = (long long)blockIdx.x * THREADS + tid;
         i < n_pairs;
         i += (long long)gridDim.x * THREADS) {
        const long long c0 = 2 * i;
        if (c0 + 1 < (long long)n_cells) {
            // fast path: both cells of the pair, fully aligned float4 loads
            float p[2 * NCH], t[2 * NCH];
            const fvec4* pp = pred4 + i * F4PP;
            const fvec4* tp = targ4 + i * F4PP;
#pragma unroll
            for (int k = 0; k < F4PP; k++) {
                fvec4 v = pp[k];
                p[4 * k] = v.x; p[4 * k + 1] = v.y; p[4 * k + 2] = v.z; p[4 * k + 3] = v.w;
            }
#pragma unroll
            for (int k = 0; k < F4PP; k++) {
                fvec4 v = tp[k];
                t[4 * k] = v.x; t[4 * k + 1] = v.y; t[4 * k + 2] = v.z; t[4 * k + 3] = v.w;
            }
            cell_losses(p, t, coord, lobj, lnoobj, lclass);
            cell_losses(p + NCH, t + NCH, coord, lobj, lnoobj, lclass);
        } else if (c0 < (long long)n_cells) {
            // odd tail: single cell, 8B-aligned float2 loads
            float p[NCH], t[NCH];
            const fvec2* pp = reinterpret_cast<const fvec2*>(pred4) + c0 * F2PC;
            const fvec2* tp = reinterpret_cast<const fvec2*>(targ4) + c0 * F2PC;
#pragma unroll
            for (int k = 0; k < F2PC; k++) { fvec2 v = pp[k]; p[2 * k] = v.x; p[2 * k + 1] = v.y; }
#pragma unroll
            for (int k = 0; k < F2PC; k++) { fvec2 v = tp[k]; t[2 * k] = v.x; t[2 * k + 1] = v.y; }
            cell_losses(p, t, coord, lobj, lnoobj, lclass);
        }
    }

    // wave-64 shuffle reduction
#pragma unroll
    for (int off = 32; off > 0; off >>= 1) {
        coord  += __shfl_down(coord, off);
        lobj   += __shfl_down(lobj, off);
        lnoobj += __shfl_down(lnoobj, off);
        lclass += __shfl_down(lclass, off);
    }

    __shared__ float red[4][4];
    int lane = tid & 63;
    int wid  = tid >> 6;
    if (lane == 0) {
        red[wid][0] = coord; red[wid][1] = lobj;
        red[wid][2] = lnoobj; red[wid][3] = lclass;
    }
    __syncthreads();
    if (tid == 0) {
        float s0 = 0.f, s1 = 0.f, s2 = 0.f, s3 = 0.f;
        for (int w = 0; w < 4; w++) {
            s0 += red[w][0]; s1 += red[w][1];
            s2 += red[w][2]; s3 += red[w][3];
        }
        partials[blockIdx.x] = make_float4(s0, s1, s2, s3);
    }
}

__global__ __launch_bounds__(THREADS) void yolo_reduce(
        const float4* __restrict__ partials, int nparts,
        float* __restrict__ out, double inv_bs) {
    double s0 = 0.0, s1 = 0.0, s2 = 0.0, s3 = 0.0;
    for (int i = threadIdx.x; i < nparts; i += THREADS) {
        float4 v = partials[i];
        s0 += (double)v.x; s1 += (double)v.y;
        s2 += (double)v.z; s3 += (double)v.w;
    }
#pragma unroll
    for (int off = 32; off > 0; off >>= 1) {
        s0 += __shfl_down(s0, off);
        s1 += __shfl_down(s1, off);
        s2 += __shfl_down(s2, off);
        s3 += __shfl_down(s3, off);
    }
    __shared__ double red[4][4];
    int lane = threadIdx.x & 63;
    int wid  = threadIdx.x >> 6;
    if (lane == 0) {
        red[wid][0] = s0; red[wid][1] = s1;
        red[wid][2] = s2; red[wid][3] = s3;
    }
    __syncthreads();
    if (threadIdx.x == 0) {
        double a0 = 0, a1 = 0, a2 = 0, a3 = 0;
        for (int w = 0; w < 4; w++) {
            a0 += red[w][0]; a1 += red[w][1];
            a2 += red[w][2]; a3 += red[w][3];
        }
        double cd = a0 * 5.0 * inv_bs;   // LAMBDA_COORD
        double o  = a1 * inv_bs;
        double n  = a2 * 0.5 * inv_bs;   // LAMBDA_NOOBJ
        double cl = a3 * inv_bs;
        out[0] = (float)cd;
        out[1] = (float)o;
        out[2] = (float)n;
        out[3] = (float)cl;
        out[4] = (float)(cd + o + n + cl);
    }
}

extern "C" void kernel_launch(void* const* d_in, const int* in_sizes, int n_in,
                              void* d_out, int out_size, void* d_ws, size_t ws_size,
                              hipStream_t stream) {
    const fvec4* pred4 = (const fvec4*)d_in[0];
    const fvec4* targ4 = (const fvec4*)d_in[1];
    float* out = (float*)d_out;
    float4* partials = (float4*)d_ws;

    int n_cells = in_sizes[0] / NCH;          // batch * 7 * 7
    int batch   = n_cells / 49;
    int n_pairs = (n_cells + 1) / 2;

    // one-shot grid: every thread handles exactly one cell-pair; the hardware
    // dispatcher load-balances blocks across CUs dynamically.
    int grid = (n_pairs + THREADS - 1) / THREADS;
    if (grid < 1) grid = 1;

    // workspace guard: if ws can't hold one float4 per block, shrink the grid
    // and let the pair-stride loop cover the rest.
    int max_parts = (int)(ws_size / sizeof(float4));
    if (max_parts >= 1 && grid > max_parts) grid = max_parts;

    yolo_main<<<grid, THREADS, 0, stream>>>(pred4, targ4, partials, n_pairs, n_cells);
    yolo_reduce<<<1, THREADS, 0, stream>>>(partials, grid, out, 1.0 / (double)batch);
}

// Round 4
// 210.589 us; speedup vs baseline: 1.0071x; 1.0071x over previous
//
#include <hip/hip_runtime.h>

#define NCH 30
#define F2PC 15              // float2 per cell (120 B)
#define TILE 64              // cells per wave-tile
#define TPB 64               // one wave per block: no barrier convoys
#define MAXB 2560            // 10 blocks/CU (LDS-capped: 10 * 15360 B < 160 KiB) * 256 CUs

typedef float fvec2 __attribute__((ext_vector_type(2)));
typedef float fvec4 __attribute__((ext_vector_type(4)));

__device__ __forceinline__ float iou_fn(float x1, float y1, float w1, float h1,
                                        float x2, float y2, float w2, float h2) {
    float a1 = w1 * h1, a2 = w2 * h2;
    float left  = fmaxf(x1 - w1 * 0.5f, x2 - w2 * 0.5f);
    float right = fminf(x1 + w1 * 0.5f, x2 + w2 * 0.5f);
    float top   = fmaxf(y1 - h1 * 0.5f, y2 - h2 * 0.5f);
    float bot   = fminf(y1 + h1 * 0.5f, y2 + h2 * 0.5f);
    float iw = fmaxf(right - left, 0.0f);
    float ih = fmaxf(bot - top, 0.0f);
    float inter = iw * ih;
    float uni = a1 + a2 - inter;
    return (inter > 0.0f) ? (inter / uni) : 0.0f;
}

__device__ __forceinline__ void cell_losses(const float* p, const float* t,
                                            float& coord, float& lobj,
                                            float& lnoobj, float& lclass) {
    float obj_f = (t[0] == 1.0f) ? 1.0f : 0.0f;

    float iou1 = iou_fn(p[1], p[2], p[3], p[4], t[1], t[2], t[3], t[4]);
    float iou2 = iou_fn(t[6], t[7], t[8], t[9], t[1], t[2], t[3], t[4]);
    bool r = iou1 > iou2;

    float px = r ? p[1] : p[6], py = r ? p[2] : p[7];
    float pw = r ? p[3] : p[8], ph = r ? p[4] : p[9];
    float tx = r ? t[1] : t[6], ty = r ? t[2] : t[7];
    float tw = r ? t[3] : t[8], th = r ? t[4] : t[9];

    float dx = px - tx, dy = py - ty;
    float cxy = dx * dx + dy * dy;
    float swv = sqrtf(pw) - sqrtf(tw), shv = sqrtf(ph) - sqrtf(th);
    float cwh = swv * swv + shv * shv;

    float conf_resp  = r ? p[0] : p[5];
    float iou_resp   = r ? iou1 : iou2;
    float conf_other = r ? p[5] : p[0];
    float dconf = conf_resp - iou_resp;

    coord  += obj_f * (cxy + cwh);
    lobj   += obj_f * dconf * dconf;
    lnoobj += obj_f * conf_other * conf_other
            + (1.0f - obj_f) * (p[0] * p[0] + p[5] * p[5]);

    float cls = 0.0f;
#pragma unroll
    for (int i = 10; i < NCH; i++) { float e = p[i] - t[i]; cls += e * e; }
    lclass += obj_f * cls;
}

// Wave-autonomous streaming: block = ONE wave owning a 64-cell tile.
// - coalesced loads: 7x dwordx4 + 1x dwordx2 per tensor per lane (1920 B/instr,
//   zero redundant lines -> L2 traffic == input bytes exactly)
// - LDS transpose per wave (15,360 B/block -> 10 independent blocks/CU)
// - depth-1 register prefetch per wave; no inter-wave barriers anywhere ->
//   10 decoupled load pipelines per CU, ~150 KB in flight per CU.
__global__ __launch_bounds__(TPB) void yolo_main(
        const float* __restrict__ pred, const float* __restrict__ targ,
        float4* __restrict__ partials, int n_full, int n_cells) {
    __shared__ fvec4 sp4[TILE * F2PC / 2];   // 7680 B (480 fvec4)
    __shared__ fvec4 st4[TILE * F2PC / 2];   // 7680 B

    const int lane = threadIdx.x;
    float coord = 0.f, lobj = 0.f, lnoobj = 0.f, lclass = 0.f;

    fvec4 rp[7], rt[7];
    fvec2 rp7, rt7;

    int t = blockIdx.x;
    bool have = t < n_full;
    if (have) {
        const long long b4 = (long long)t * 480;     // tile base in fvec4 units
#pragma unroll
        for (int k = 0; k < 7; k++) {
            rp[k] = reinterpret_cast<const fvec4*>(pred)[b4 + k * 64 + lane];
            rt[k] = reinterpret_cast<const fvec4*>(targ)[b4 + k * 64 + lane];
        }
        rp7 = reinterpret_cast<const fvec2*>(pred)[2 * b4 + 896 + lane];
        rt7 = reinterpret_cast<const fvec2*>(targ)[2 * b4 + 896 + lane];
    }

    while (have) {
        const int tn = t + gridDim.x;
        const bool have_n = tn < n_full;

        __syncthreads();                      // 1-wave block: trivial, no convoy
#pragma unroll
        for (int k = 0; k < 7; k++) {         // fill LDS (ds_write_b128, waits vmcnt per-store)
            sp4[k * 64 + lane] = rp[k];
            st4[k * 64 + lane] = rt[k];
        }
        reinterpret_cast<fvec2*>(sp4)[896 + lane] = rp7;
        reinterpret_cast<fvec2*>(st4)[896 + lane] = rt7;
        __syncthreads();

        if (have_n) {                         // prefetch next tile; in flight across compute
            const long long b4 = (long long)tn * 480;
#pragma unroll
            for (int k = 0; k < 7; k++) {
                rp[k] = reinterpret_cast<const fvec4*>(pred)[b4 + k * 64 + lane];
                rt[k] = reinterpret_cast<const fvec4*>(targ)[b4 + k * 64 + lane];
            }
            rp7 = reinterpret_cast<const fvec2*>(pred)[2 * b4 + 896 + lane];
            rt7 = reinterpret_cast<const fvec2*>(targ)[2 * b4 + 896 + lane];
        }

        // compute: one cell per lane
        {
            float p[NCH], tt[NCH];
            const fvec2* pp = reinterpret_cast<const fvec2*>(sp4) + lane * F2PC;
            const fvec2* tp = reinterpret_cast<const fvec2*>(st4) + lane * F2PC;
#pragma unroll
            for (int k = 0; k < F2PC; k++) { fvec2 v = pp[k]; p[2 * k] = v.x; p[2 * k + 1] = v.y; }
#pragma unroll
            for (int k = 0; k < F2PC; k++) { fvec2 v = tp[k]; tt[2 * k] = v.x; tt[2 * k + 1] = v.y; }
            cell_losses(p, tt, coord, lobj, lnoobj, lclass);
        }

        t = tn; have = have_n;
    }

    // tail cells (n_cells % TILE — zero for the bench shape), block 0, direct loads
    if (blockIdx.x == 0) {
        int cell = n_full * TILE + lane;
        if (cell < n_cells) {
            float p[NCH], tt[NCH];
            const fvec2* pp = reinterpret_cast<const fvec2*>(pred) + (long long)cell * F2PC;
            const fvec2* tp = reinterpret_cast<const fvec2*>(targ) + (long long)cell * F2PC;
#pragma unroll
            for (int k = 0; k < F2PC; k++) { fvec2 v = pp[k]; p[2 * k] = v.x; p[2 * k + 1] = v.y; }
#pragma unroll
            for (int k = 0; k < F2PC; k++) { fvec2 v = tp[k]; tt[2 * k] = v.x; tt[2 * k + 1] = v.y; }
            cell_losses(p, tt, coord, lobj, lnoobj, lclass);
        }
    }

    // single-wave shuffle reduction
#pragma unroll
    for (int off = 32; off > 0; off >>= 1) {
        coord  += __shfl_down(coord, off);
        lobj   += __shfl_down(lobj, off);
        lnoobj += __shfl_down(lnoobj, off);
        lclass += __shfl_down(lclass, off);
    }
    if (lane == 0) partials[blockIdx.x] = make_float4(coord, lobj, lnoobj, lclass);
}

__global__ __launch_bounds__(256) void yolo_reduce(
        const float4* __restrict__ partials, int nparts,
        float* __restrict__ out, double inv_bs) {
    double s0 = 0.0, s1 = 0.0, s2 = 0.0, s3 = 0.0;
    for (int i = threadIdx.x; i < nparts; i += 256) {
        float4 v = partials[i];
        s0 += (double)v.x; s1 += (double)v.y;
        s2 += (double)v.z; s3 += (double)v.w;
    }
#pragma unroll
    for (int off = 32; off > 0; off >>= 1) {
        s0 += __shfl_down(s0, off);
        s1 += __shfl_down(s1, off);
        s2 += __shfl_down(s2, off);
        s3 += __shfl_down(s3, off);
    }
    __shared__ double red[4][4];
    int lane = threadIdx.x & 63;
    int wid  = threadIdx.x >> 6;
    if (lane == 0) {
        red[wid][0] = s0; red[wid][1] = s1;
        red[wid][2] = s2; red[wid][3] = s3;
    }
    __syncthreads();
    if (threadIdx.x == 0) {
        double a0 = 0, a1 = 0, a2 = 0, a3 = 0;
        for (int w = 0; w < 4; w++) {
            a0 += red[w][0]; a1 += red[w][1];
            a2 += red[w][2]; a3 += red[w][3];
        }
        double cd = a0 * 5.0 * inv_bs;   // LAMBDA_COORD
        double o  = a1 * inv_bs;
        double n  = a2 * 0.5 * inv_bs;   // LAMBDA_NOOBJ
        double cl = a3 * inv_bs;
        out[0] = (float)cd;
        out[1] = (float)o;
        out[2] = (float)n;
        out[3] = (float)cl;
        out[4] = (float)(cd + o + n + cl);
    }
}

extern "C" void kernel_launch(void* const* d_in, const int* in_sizes, int n_in,
                              void* d_out, int out_size, void* d_ws, size_t ws_size,
                              hipStream_t stream) {
    const float* pred = (const float*)d_in[0];
    const float* targ = (const float*)d_in[1];
    float* out = (float*)d_out;
    float4* partials = (float4*)d_ws;

    int n_cells = in_sizes[0] / NCH;          // batch * 7 * 7
    int batch   = n_cells / 49;
    int n_full  = n_cells / TILE;

    int grid = (n_full < 1) ? 1 : (n_full < MAXB ? n_full : MAXB);

    // workspace guard: one float4 per block
    int max_parts = (int)(ws_size / sizeof(float4));
    if (max_parts >= 1 && grid > max_parts) grid = max_parts;

    yolo_main<<<grid, TPB, 0, stream>>>(pred, targ, partials, n_full, n_cells);
    yolo_reduce<<<1, 256, 0, stream>>>(partials, grid, out, 1.0 / (double)batch);
}

// Round 5
// 189.566 us; speedup vs baseline: 1.1188x; 1.1109x over previous
//
#include <hip/hip_runtime.h>

#define NCH 30
#define F2PC 15              // float2 per cell (120 B)
#define TILE 64              // cells per wave-tile
#define TPB 64               // one wave per block: no barrier convoys
#define MAXB 2560            // 10 blocks/CU (LDS-capped: 10 * 15360 B < 160 KiB) * 256 CUs

typedef float fvec2 __attribute__((ext_vector_type(2)));
typedef float fvec4 __attribute__((ext_vector_type(4)));

__device__ __forceinline__ float iou_fn(float x1, float y1, float w1, float h1,
                                        float x2, float y2, float w2, float h2) {
    float a1 = w1 * h1, a2 = w2 * h2;
    float left  = fmaxf(x1 - w1 * 0.5f, x2 - w2 * 0.5f);
    float right = fminf(x1 + w1 * 0.5f, x2 + w2 * 0.5f);
    float top   = fmaxf(y1 - h1 * 0.5f, y2 - h2 * 0.5f);
    float bot   = fminf(y1 + h1 * 0.5f, y2 + h2 * 0.5f);
    float iw = fmaxf(right - left, 0.0f);
    float ih = fmaxf(bot - top, 0.0f);
    float inter = iw * ih;
    float uni = a1 + a2 - inter;
    return (inter > 0.0f) ? (inter / uni) : 0.0f;
}

__device__ __forceinline__ void cell_losses(const float* p, const float* t,
                                            float& coord, float& lobj,
                                            float& lnoobj, float& lclass) {
    float obj_f = (t[0] == 1.0f) ? 1.0f : 0.0f;

    float iou1 = iou_fn(p[1], p[2], p[3], p[4], t[1], t[2], t[3], t[4]);
    float iou2 = iou_fn(t[6], t[7], t[8], t[9], t[1], t[2], t[3], t[4]);
    bool r = iou1 > iou2;

    float px = r ? p[1] : p[6], py = r ? p[2] : p[7];
    float pw = r ? p[3] : p[8], ph = r ? p[4] : p[9];
    float tx = r ? t[1] : t[6], ty = r ? t[2] : t[7];
    float tw = r ? t[3] : t[8], th = r ? t[4] : t[9];

    float dx = px - tx, dy = py - ty;
    float cxy = dx * dx + dy * dy;
    float swv = sqrtf(pw) - sqrtf(tw), shv = sqrtf(ph) - sqrtf(th);
    float cwh = swv * swv + shv * shv;

    float conf_resp  = r ? p[0] : p[5];
    float iou_resp   = r ? iou1 : iou2;
    float conf_other = r ? p[5] : p[0];
    float dconf = conf_resp - iou_resp;

    coord  += obj_f * (cxy + cwh);
    lobj   += obj_f * dconf * dconf;
    lnoobj += obj_f * conf_other * conf_other
            + (1.0f - obj_f) * (p[0] * p[0] + p[5] * p[5]);

    float cls = 0.0f;
#pragma unroll
    for (int i = 10; i < NCH; i++) { float e = p[i] - t[i]; cls += e * e; }
    lclass += obj_f * cls;
}

// Round-4 structure UNCHANGED except: all hot-loop global loads are
// __builtin_nontemporal_load (single-variable A/B vs round 4).
// History: NT variants (r0/r1) -> yolo_main ~50us inferred; plain variants
// (r2/r3/r4) -> 72-78us measured, across three unrelated structures.
__global__ __launch_bounds__(TPB) void yolo_main(
        const float* __restrict__ pred, const float* __restrict__ targ,
        float4* __restrict__ partials, int n_full, int n_cells) {
    __shared__ fvec4 sp4[TILE * F2PC / 2];   // 7680 B (480 fvec4)
    __shared__ fvec4 st4[TILE * F2PC / 2];   // 7680 B

    const int lane = threadIdx.x;
    float coord = 0.f, lobj = 0.f, lnoobj = 0.f, lclass = 0.f;

    fvec4 rp[7], rt[7];
    fvec2 rp7, rt7;

    int t = blockIdx.x;
    bool have = t < n_full;
    if (have) {
        const long long b4 = (long long)t * 480;     // tile base in fvec4 units
#pragma unroll
        for (int k = 0; k < 7; k++) {
            rp[k] = __builtin_nontemporal_load(reinterpret_cast<const fvec4*>(pred) + b4 + k * 64 + lane);
            rt[k] = __builtin_nontemporal_load(reinterpret_cast<const fvec4*>(targ) + b4 + k * 64 + lane);
        }
        rp7 = __builtin_nontemporal_load(reinterpret_cast<const fvec2*>(pred) + 2 * b4 + 896 + lane);
        rt7 = __builtin_nontemporal_load(reinterpret_cast<const fvec2*>(targ) + 2 * b4 + 896 + lane);
    }

    while (have) {
        const int tn = t + gridDim.x;
        const bool have_n = tn < n_full;

        __syncthreads();                      // 1-wave block: trivial, no convoy
#pragma unroll
        for (int k = 0; k < 7; k++) {         // fill LDS (ds_write_b128, waits vmcnt per-store)
            sp4[k * 64 + lane] = rp[k];
            st4[k * 64 + lane] = rt[k];
        }
        reinterpret_cast<fvec2*>(sp4)[896 + lane] = rp7;
        reinterpret_cast<fvec2*>(st4)[896 + lane] = rt7;
        __syncthreads();

        if (have_n) {                         // prefetch next tile; in flight across compute
            const long long b4 = (long long)tn * 480;
#pragma unroll
            for (int k = 0; k < 7; k++) {
                rp[k] = __builtin_nontemporal_load(reinterpret_cast<const fvec4*>(pred) + b4 + k * 64 + lane);
                rt[k] = __builtin_nontemporal_load(reinterpret_cast<const fvec4*>(targ) + b4 + k * 64 + lane);
            }
            rp7 = __builtin_nontemporal_load(reinterpret_cast<const fvec2*>(pred) + 2 * b4 + 896 + lane);
            rt7 = __builtin_nontemporal_load(reinterpret_cast<const fvec2*>(targ) + 2 * b4 + 896 + lane);
        }

        // compute: one cell per lane
        {
            float p[NCH], tt[NCH];
            const fvec2* pp = reinterpret_cast<const fvec2*>(sp4) + lane * F2PC;
            const fvec2* tp = reinterpret_cast<const fvec2*>(st4) + lane * F2PC;
#pragma unroll
            for (int k = 0; k < F2PC; k++) { fvec2 v = pp[k]; p[2 * k] = v.x; p[2 * k + 1] = v.y; }
#pragma unroll
            for (int k = 0; k < F2PC; k++) { fvec2 v = tp[k]; tt[2 * k] = v.x; tt[2 * k + 1] = v.y; }
            cell_losses(p, tt, coord, lobj, lnoobj, lclass);
        }

        t = tn; have = have_n;
    }

    // tail cells (n_cells % TILE — zero for the bench shape), block 0, direct loads
    if (blockIdx.x == 0) {
        int cell = n_full * TILE + lane;
        if (cell < n_cells) {
            float p[NCH], tt[NCH];
            const fvec2* pp = reinterpret_cast<const fvec2*>(pred) + (long long)cell * F2PC;
            const fvec2* tp = reinterpret_cast<const fvec2*>(targ) + (long long)cell * F2PC;
#pragma unroll
            for (int k = 0; k < F2PC; k++) { fvec2 v = pp[k]; p[2 * k] = v.x; p[2 * k + 1] = v.y; }
#pragma unroll
            for (int k = 0; k < F2PC; k++) { fvec2 v = tp[k]; tt[2 * k] = v.x; tt[2 * k + 1] = v.y; }
            cell_losses(p, tt, coord, lobj, lnoobj, lclass);
        }
    }

    // single-wave shuffle reduction
#pragma unroll
    for (int off = 32; off > 0; off >>= 1) {
        coord  += __shfl_down(coord, off);
        lobj   += __shfl_down(lobj, off);
        lnoobj += __shfl_down(lnoobj, off);
        lclass += __shfl_down(lclass, off);
    }
    if (lane == 0) partials[blockIdx.x] = make_float4(coord, lobj, lnoobj, lclass);
}

__global__ __launch_bounds__(256) void yolo_reduce(
        const float4* __restrict__ partials, int nparts,
        float* __restrict__ out, double inv_bs) {
    double s0 = 0.0, s1 = 0.0, s2 = 0.0, s3 = 0.0;
    for (int i = threadIdx.x; i < nparts; i += 256) {
        float4 v = partials[i];
        s0 += (double)v.x; s1 += (double)v.y;
        s2 += (double)v.z; s3 += (double)v.w;
    }
#pragma unroll
    for (int off = 32; off > 0; off >>= 1) {
        s0 += __shfl_down(s0, off);
        s1 += __shfl_down(s1, off);
        s2 += __shfl_down(s2, off);
        s3 += __shfl_down(s3, off);
    }
    __shared__ double red[4][4];
    int lane = threadIdx.x & 63;
    int wid  = threadIdx.x >> 6;
    if (lane == 0) {
        red[wid][0] = s0; red[wid][1] = s1;
        red[wid][2] = s2; red[wid][3] = s3;
    }
    __syncthreads();
    if (threadIdx.x == 0) {
        double a0 = 0, a1 = 0, a2 = 0, a3 = 0;
        for (int w = 0; w < 4; w++) {
            a0 += red[w][0]; a1 += red[w][1];
            a2 += red[w][2]; a3 += red[w][3];
        }
        double cd = a0 * 5.0 * inv_bs;   // LAMBDA_COORD
        double o  = a1 * inv_bs;
        double n  = a2 * 0.5 * inv_bs;   // LAMBDA_NOOBJ
        double cl = a3 * inv_bs;
        out[0] = (float)cd;
        out[1] = (float)o;
        out[2] = (float)n;
        out[3] = (float)cl;
        out[4] = (float)(cd + o + n + cl);
    }
}

extern "C" void kernel_launch(void* const* d_in, const int* in_sizes, int n_in,
                              void* d_out, int out_size, void* d_ws, size_t ws_size,
                              hipStream_t stream) {
    const float* pred = (const float*)d_in[0];
    const float* targ = (const float*)d_in[1];
    float* out = (float*)d_out;
    float4* partials = (float4*)d_ws;

    int n_cells = in_sizes[0] / NCH;          // batch * 7 * 7
    int batch   = n_cells / 49;
    int n_full  = n_cells / TILE;

    int grid = (n_full < 1) ? 1 : (n_full < MAXB ? n_full : MAXB);

    // workspace guard: one float4 per block
    int max_parts = (int)(ws_size / sizeof(float4));
    if (max_parts >= 1 && grid > max_parts) grid = max_parts;

    yolo_main<<<grid, TPB, 0, stream>>>(pred, targ, partials, n_full, n_cells);
    yolo_reduce<<<1, 256, 0, stream>>>(partials, grid, out, 1.0 / (double)batch);
}